// Round 13
// baseline (482.133 us; speedup 1.0000x reference)
//
#include <hip/hip_runtime.h>
#include <hip/hip_bf16.h>

// Problem constants (from reference)
#define N_NODES  100000
#define N_EDGES  400000
#define N_GRAPHS 4000
#define IN_DIM   128
#define HID      512
#define N_DESC   200
#define N_CLASSES 2
#define MLP1_OUT 500
#define MLP2_OUT 100
#define XIN_DIM  (HID + N_DESC)   // 712
#define XIN_PAD  768              // K padded to multiple of 64

#define SCAN_CHUNK 1024
#define NCHK ((N_NODES + SCAN_CHUNK - 1) / SCAN_CHUNK)   // 98

typedef __hip_bfloat16  bf16;
typedef __hip_bfloat162 bf16x2;
typedef short s8v  __attribute__((ext_vector_type(8)));   // 8 bf16 (4 VGPRs)
typedef float f32x4 __attribute__((ext_vector_type(4)));

// ---------------------------------------------------------------------------
// Dtype-generic helpers (FT = float or bf16), all produce fp32.
// ---------------------------------------------------------------------------
__device__ __forceinline__ float ldf(const float* p, size_t i) { return p[i]; }
__device__ __forceinline__ float ldf(const bf16* p, size_t i)  { return __bfloat162float(p[i]); }

__device__ __forceinline__ float2 ld2(const float* p, int i) { return ((const float2*)p)[i]; }
__device__ __forceinline__ float2 ld2(const bf16* p, int i)  {
    return __bfloat1622float2(((const bf16x2*)p)[i]);
}

__device__ __forceinline__ short f2bs(float x) {
    bf16 h = __float2bfloat16(x);
    return __builtin_bit_cast(short, h);
}

// async global->LDS, 16B per lane; LDS dest = wave-uniform base + lane*16
__device__ __forceinline__ void gld16(const short* g, short* l) {
    __builtin_amdgcn_global_load_lds(
        (const __attribute__((address_space(1))) unsigned int*)g,
        (__attribute__((address_space(3))) unsigned int*)l, 16, 0, 0);
}

// ---------------------------------------------------------------------------
// Runtime dtype detection (flag: 0=fp32, 1=bf16); see round-5 notes.
// ---------------------------------------------------------------------------
__global__ __launch_bounds__(256)
void detect_dtype_kernel(const unsigned* __restrict__ words, unsigned nw,
                         int* __restrict__ flag)
{
    __shared__ int s_cnt;
    if (threadIdx.x == 0) s_cnt = 0;
    __syncthreads();
    const int SAMPLES = 2048;
    int sane = 0;
    for (int i = threadIdx.x; i < SAMPLES; i += 256) {
        size_t idx = (size_t)(((unsigned long long)i * 2654435761ull) % nw);
        unsigned w = words[idx];
        float f = __uint_as_float((w & 0xFFFFu) << 16);
        float a = fabsf(f);
        if (f == 0.0f || (a > 1e-8f && a < 1e8f)) sane++;
    }
    atomicAdd(&s_cnt, sane);
    __syncthreads();
    if (threadIdx.x == 0) *flag = (s_cnt * 10 > SAMPLES * 6) ? 1 : 0;
}

// ---------------------------------------------------------------------------
// Fused weight prep (runtime dual-mode): weights -> transposed bf16 [N][K]
// (zero-pad), biases -> fp32 (zero-pad). Segments: W1t 65536 | W2t 262144 |
// lw1t 393216 | lw2t 65536 | b1f 512 | b2f 512 | lb1f 512 | lb2f 128
// ---------------------------------------------------------------------------
__global__ __launch_bounds__(256)
void prep_weights_kernel(const void* __restrict__ W1, const void* __restrict__ W2,
                         const void* __restrict__ lw1, const void* __restrict__ lw2,
                         const void* __restrict__ b1, const void* __restrict__ b2,
                         const void* __restrict__ lb1, const void* __restrict__ lb2,
                         short* __restrict__ W1t, short* __restrict__ W2t,
                         short* __restrict__ lw1t, short* __restrict__ lw2t,
                         float* __restrict__ b1f, float* __restrict__ b2f,
                         float* __restrict__ lb1f, float* __restrict__ lb2f,
                         const int* __restrict__ flag)
{
    const int bf = *flag;
    auto rd = [&](const void* p, size_t idx) -> float {
        return bf ? __bfloat162float(((const bf16*)p)[idx]) : ((const float*)p)[idx];
    };
    int i = blockIdx.x * 256 + threadIdx.x;
    if (i < 65536) {            // W1t [512][128] <- W1 [128,512]
        int n = i >> 7, k = i & 127;
        W1t[i] = f2bs(rd(W1, (size_t)k * HID + n));
        return;
    }
    i -= 65536;
    if (i < 262144) {           // W2t [512][512] <- W2 [512,512]
        int n = i >> 9, k = i & 511;
        W2t[i] = f2bs(rd(W2, (size_t)k * HID + n));
        return;
    }
    i -= 262144;
    if (i < 393216) {           // lw1t [512][768] <- lw1 [712,500], zero-pad
        int n = i / XIN_PAD, k = i - n * XIN_PAD;
        lw1t[i] = (n < MLP1_OUT && k < XIN_DIM)
                      ? f2bs(rd(lw1, (size_t)k * MLP1_OUT + n)) : (short)0;
        return;
    }
    i -= 393216;
    if (i < 65536) {            // lw2t [128][512] <- lw2 [500,100], zero-pad
        int n = i >> 9, k = i & 511;
        lw2t[i] = (n < MLP2_OUT && k < MLP1_OUT)
                      ? f2bs(rd(lw2, (size_t)k * MLP2_OUT + n)) : (short)0;
        return;
    }
    i -= 65536;
    if (i < 512) { b1f[i] = rd(b1, i); return; }
    i -= 512;
    if (i < 512) { b2f[i] = rd(b2, i); return; }
    i -= 512;
    if (i < 512) { lb1f[i] = (i < MLP1_OUT) ? rd(lb1, i) : 0.f; return; }
    i -= 512;
    if (i < 128) { lb2f[i] = (i < MLP2_OUT) ? rd(lb2, i) : 0.f; return; }
}

// ---------------------------------------------------------------------------
// CSR build: deg histogram -> two-level exclusive scan -> fill
// ---------------------------------------------------------------------------
__global__ __launch_bounds__(256)
void deg_kernel(const int* __restrict__ dst, int* __restrict__ deg)
{
    int e = blockIdx.x * 256 + threadIdx.x;
    if (e < N_EDGES) atomicAdd(&deg[dst[e]], 1);
}

__global__ __launch_bounds__(256)
void scan_partial_kernel(const int* __restrict__ deg, int* __restrict__ part)
{
    int c = blockIdx.x, t = threadIdx.x;
    int i0 = c * SCAN_CHUNK + t * 4;
    int s = 0;
#pragma unroll
    for (int j = 0; j < 4; j++) {
        int i = i0 + j;
        if (i < N_NODES) s += deg[i];
    }
    __shared__ int red[256];
    red[t] = s;
    __syncthreads();
    for (int off = 128; off > 0; off >>= 1) {
        if (t < off) red[t] += red[t + off];
        __syncthreads();
    }
    if (t == 0) part[c] = red[0];
}

__global__ void scan_parts_kernel(int* __restrict__ part, int* __restrict__ edge_start)
{
    int run = 0;
    for (int c = 0; c < NCHK; c++) { int v = part[c]; part[c] = run; run += v; }
    edge_start[N_NODES] = run;
}

// also initializes cursor[] (saves a dispatch)
__global__ __launch_bounds__(256)
void scan_final_kernel(const int* __restrict__ deg, const int* __restrict__ part,
                       int* __restrict__ edge_start, int* __restrict__ cursor)
{
    int c = blockIdx.x, t = threadIdx.x;
    int i0 = c * SCAN_CHUNK + t * 4;
    int d[4];
    int tsum = 0;
#pragma unroll
    for (int j = 0; j < 4; j++) {
        int i = i0 + j;
        d[j] = (i < N_NODES) ? deg[i] : 0;
        tsum += d[j];
    }
    __shared__ int s[256];
    s[t] = tsum;
    __syncthreads();
    for (int off = 1; off < 256; off <<= 1) {
        int v = (t >= off) ? s[t - off] : 0;
        __syncthreads();
        s[t] += v;
        __syncthreads();
    }
    int run = part[c] + s[t] - tsum;
#pragma unroll
    for (int j = 0; j < 4; j++) {
        int i = i0 + j;
        if (i < N_NODES) { edge_start[i] = run; cursor[i] = run; run += d[j]; }
    }
}

__global__ __launch_bounds__(256)
void fill_kernel(const int* __restrict__ src, const int* __restrict__ dst,
                 int* __restrict__ cursor, int* __restrict__ csr_src)
{
    int e = blockIdx.x * 256 + threadIdx.x;
    if (e >= N_EDGES) return;
    int p = atomicAdd(&cursor[dst[e]], 1);
    csr_src[p] = src[e];
}

// gstart[g] = first node index with node2graph >= g (node2graph sorted)
__global__ __launch_bounds__(256)
void gstart_kernel(const int* __restrict__ n2g, int* __restrict__ gstart)
{
    int n = blockIdx.x * 256 + threadIdx.x;
    if (n > N_NODES) return;
    if (n == N_NODES) {
        int last = n2g[N_NODES - 1];
        for (int g = last + 1; g <= N_GRAPHS; g++) gstart[g] = N_NODES;
        return;
    }
    int v = n2g[n];
    int prev = (n == 0) ? -1 : n2g[n - 1];
    for (int g = prev + 1; g <= v; g++) gstart[g] = n;
}

// ---------------------------------------------------------------------------
// Layer-1 gather (4x unrolled edge loop -> 4 loads in flight; latency-bound
// stage): agg1[n,0:128] = sum_{e: dst=n} feat[src[e],0:128]  (bf16 out)
// ---------------------------------------------------------------------------
template<typename FT>
__device__ __forceinline__ void gather_feat_body(const FT* __restrict__ feat,
                                                 const int* __restrict__ edge_start,
                                                 const int* __restrict__ csr_src,
                                                 bf16* __restrict__ agg1)
{
    int n = blockIdx.x * 4 + (threadIdx.x >> 6);
    if (n >= N_NODES) return;
    int lane = threadIdx.x & 63;
    int e0 = edge_start[n], e1 = edge_start[n + 1];
    float2 acc = {0.f, 0.f};
    int i = e0;
    for (; i + 4 <= e1; i += 4) {
        int s0 = csr_src[i], s1 = csr_src[i + 1];
        int s2 = csr_src[i + 2], s3 = csr_src[i + 3];
        float2 f0 = ld2(feat + (size_t)s0 * IN_DIM, lane);
        float2 f1 = ld2(feat + (size_t)s1 * IN_DIM, lane);
        float2 f2 = ld2(feat + (size_t)s2 * IN_DIM, lane);
        float2 f3 = ld2(feat + (size_t)s3 * IN_DIM, lane);
        acc.x += (f0.x + f1.x) + (f2.x + f3.x);
        acc.y += (f0.y + f1.y) + (f2.y + f3.y);
    }
    for (; i < e1; i++) {
        int s = csr_src[i];
        float2 f = ld2(feat + (size_t)s * IN_DIM, lane);
        acc.x += f.x; acc.y += f.y;
    }
    bf16x2 p;
    p.x = __float2bfloat16(acc.x);
    p.y = __float2bfloat16(acc.y);
    ((bf16x2*)(agg1 + (size_t)n * IN_DIM))[lane] = p;
}

__global__ __launch_bounds__(256)
void gather_feat_kernel(const void* __restrict__ feat, const int* __restrict__ edge_start,
                        const int* __restrict__ csr_src, bf16* __restrict__ agg1,
                        const int* __restrict__ flag)
{
    if (*flag) gather_feat_body((const bf16*)feat, edge_start, csr_src, agg1);
    else       gather_feat_body((const float*)feat, edge_start, csr_src, agg1);
}

// ---------------------------------------------------------------------------
// Layer-2 gather (4x unrolled): aggc[n,0:512] = sum h1[src,0:512] (bf16 out)
// ---------------------------------------------------------------------------
__device__ __forceinline__ void acc8(float* acc, float4 r)
{
    const bf16x2* p = (const bf16x2*)&r;
#pragma unroll
    for (int q = 0; q < 4; q++) {
        float2 f = __bfloat1622float2(p[q]);
        acc[2 * q] += f.x; acc[2 * q + 1] += f.y;
    }
}

__global__ __launch_bounds__(256)
void gather_h_kernel(const bf16* __restrict__ h1, const int* __restrict__ edge_start,
                     const int* __restrict__ csr_src, bf16* __restrict__ aggc)
{
    int n = blockIdx.x * 4 + (threadIdx.x >> 6);
    if (n >= N_NODES) return;
    int lane = threadIdx.x & 63;
    int e0 = edge_start[n], e1 = edge_start[n + 1];
    float acc[8];
#pragma unroll
    for (int j = 0; j < 8; j++) acc[j] = 0.f;
    int i = e0;
    for (; i + 4 <= e1; i += 4) {
        int s0 = csr_src[i], s1 = csr_src[i + 1];
        int s2 = csr_src[i + 2], s3 = csr_src[i + 3];
        float4 r0 = ((const float4*)(h1 + (size_t)s0 * HID))[lane];
        float4 r1 = ((const float4*)(h1 + (size_t)s1 * HID))[lane];
        float4 r2 = ((const float4*)(h1 + (size_t)s2 * HID))[lane];
        float4 r3 = ((const float4*)(h1 + (size_t)s3 * HID))[lane];
        acc8(acc, r0); acc8(acc, r1); acc8(acc, r2); acc8(acc, r3);
    }
    for (; i < e1; i++) {
        int s = csr_src[i];
        acc8(acc, ((const float4*)(h1 + (size_t)s * HID))[lane]);
    }
    s8v s;
#pragma unroll
    for (int j = 0; j < 8; j++) s[j] = f2bs(acc[j]);
    ((float4*)(aggc + (size_t)n * HID))[lane] = __builtin_bit_cast(float4, s);
}

// ---------------------------------------------------------------------------
// MFMA bf16 GEMM (m97-style + XOR-swizzled LDS + two-phase LDS epilogue +
// XCD-colocating block swizzle): C = relu(A @ Bt^T + b).
// 128x128 tile, BK=64, 4 waves (2x2 of 64x64), 16x16x32 MFMA,
// global_load_lds(16B) staging into unpadded LDS [128][64].
// Two-phase epilogue (64 rows/phase) keeps LDS at exactly 32768 B ->
// 5 blocks/CU (round-12 was 34816 B -> 4 blocks/CU).
// 1D grid, decode: r8=b&7, t=b>>3, y=t%NCT, x=(t/NCT)*8+r8 -> all NCT
// col-tiles of a row-tile share id%8 -> same XCD, A fetched once per L2
// (verified round 12: FETCH 204 -> 55 MB).
// Frag layouts per guide §3 (m89/m91): A:[m=lane&15][k=(lane>>4)*8+j],
// C/D: col=lane&15, row=(lane>>4)*4+reg.
// ---------------------------------------------------------------------------
template<int NCT>
__global__ __launch_bounds__(256)
void mfma_gemm_kernel(const short* __restrict__ A, const short* __restrict__ Bt,
                      const float* __restrict__ biasf, bf16* __restrict__ Cout,
                      int M, int K, int nrt)
{
    __shared__ short smem[16384];    // 32768 B exactly
    short* As = smem;                // 8192 shorts
    short* Bs = smem + 8192;         // 8192 shorts
    short* Cs = smem;                // epilogue alias: 64 x 136 = 8704 shorts

    // XCD-colocating decode
    const int b  = blockIdx.x;
    const int r8 = b & 7;
    const int t  = b >> 3;
    const int x  = (t / NCT) * 8 + r8;
    const int y  = t % NCT;
    if (x >= nrt) return;
    const int row0 = x * 128;
    const int col0 = y * 128;

    const int tid  = threadIdx.x;
    const int lane = tid & 63;
    const int w    = tid >> 6;
    const int wr = w >> 1, wc = w & 1;
    const int m  = lane & 15, q = lane >> 4;

    // Staging: 4 A-chunks + 4 B-chunks per wave (1 KB each). Chunk c covers
    // rows (w*4+c)*8..+7. Lane l -> row +(l>>3), global col ((l&7)^(l>>3))*8.
    const int dr = lane >> 3;
    const int dc = ((lane & 7) ^ dr) * 8;   // XOR swizzle (coalescing preserved)
    const short* ga[4];
    const short* gb[4];
    short* la[4];
    short* lb[4];
#pragma unroll
    for (int c = 0; c < 4; c++) {
        int r = (w * 4 + c) * 8 + dr;
        ga[c] = A  + (size_t)(row0 + r) * K + dc;   // OOB rows: harmless in-ws garbage
        gb[c] = Bt + (size_t)(col0 + r) * K + dc;   // Bt always padded to grid cols
        la[c] = As + (w * 4 + c) * 512;
        lb[c] = Bs + (w * 4 + c) * 512;
    }

    // Fragment-read swizzled chunk offset (shorts): kq=0 -> sa, kq=1 -> sa^32
    const int sa = ((q ^ (m & 7)) * 8);

    f32x4 acc[4][4];
#pragma unroll
    for (int i = 0; i < 4; i++)
#pragma unroll
        for (int j = 0; j < 4; j++) acc[i][j] = {0.f, 0.f, 0.f, 0.f};

    for (int k0 = 0; k0 < K; k0 += 64) {
#pragma unroll
        for (int c = 0; c < 4; c++) gld16(ga[c], la[c]);
#pragma unroll
        for (int c = 0; c < 4; c++) gld16(gb[c], lb[c]);
#pragma unroll
        for (int c = 0; c < 4; c++) { ga[c] += 64; gb[c] += 64; }
        __syncthreads();   // compiler emits s_waitcnt vmcnt(0) before barrier

#pragma unroll
        for (int kq = 0; kq < 2; kq++) {
            const int so = sa ^ (kq * 32);
            s8v av[4], bv[4];
#pragma unroll
            for (int rt = 0; rt < 4; rt++)
                av[rt] = *(const s8v*)&As[(wr * 64 + rt * 16 + m) * 64 + so];
#pragma unroll
            for (int ct = 0; ct < 4; ct++)
                bv[ct] = *(const s8v*)&Bs[(wc * 64 + ct * 16 + m) * 64 + so];
#pragma unroll
            for (int rt = 0; rt < 4; rt++)
#pragma unroll
                for (int ct = 0; ct < 4; ct++)
                    acc[rt][ct] = __builtin_amdgcn_mfma_f32_16x16x32_bf16(
                        av[rt], bv[ct], acc[rt][ct], 0, 0, 0);
        }
        __syncthreads();
    }

    // Two-phase epilogue: half = wr band (64 rows); waves with wr==half write
    // their relu(acc+bias) into Cs (stride 136 -> worst 2-way bank aliasing),
    // then all 256 threads store 64 rows x 128 cols as coalesced 16B chunks.
#pragma unroll
    for (int half = 0; half < 2; half++) {
        if (half == 1) __syncthreads();   // protect Cs reads of phase 0
        if (wr == half) {
#pragma unroll
            for (int rt = 0; rt < 4; rt++) {
#pragma unroll
                for (int ct = 0; ct < 4; ct++) {
                    int lcol = wc * 64 + ct * 16 + m;
                    float bv = biasf[col0 + lcol];
#pragma unroll
                    for (int reg = 0; reg < 4; reg++) {
                        int lrow = rt * 16 + q * 4 + reg;   // 0..63
                        float v = acc[rt][ct][reg] + bv;
                        v = v > 0.f ? v : 0.f;
                        Cs[lrow * 136 + lcol] = f2bs(v);
                    }
                }
            }
        }
        __syncthreads();
#pragma unroll
        for (int it = 0; it < 4; it++) {
            int idx = it * 256 + tid;       // 0..1023
            int r = idx >> 4;               // 0..63
            int c = (idx & 15) * 8;
            int row = row0 + half * 64 + r;
            if (row < M)
                *(float4*)&Cout[(size_t)row * HID + col0 + c] =
                    *(const float4*)&Cs[r * 136 + c];
        }
    }
}

// ---------------------------------------------------------------------------
// Graph mean-pool numerator (4x unrolled), NO atomics: wave per graph.
// hg[g, :] = sum_{n in [gstart[g], gstart[g+1])} h2[n, :]
// ---------------------------------------------------------------------------
__global__ __launch_bounds__(256)
void pool_graph_kernel(const bf16* __restrict__ h2, const int* __restrict__ gstart,
                       float* __restrict__ hg)
{
    int g = blockIdx.x * 4 + (threadIdx.x >> 6);
    if (g >= N_GRAPHS) return;
    int lane = threadIdx.x & 63;
    int s0 = gstart[g], s1 = gstart[g + 1];
    float acc[8];
#pragma unroll
    for (int j = 0; j < 8; j++) acc[j] = 0.f;
    int n = s0;
    for (; n + 4 <= s1; n += 4) {
        float4 r0 = ((const float4*)(h2 + (size_t)(n + 0) * HID))[lane];
        float4 r1 = ((const float4*)(h2 + (size_t)(n + 1) * HID))[lane];
        float4 r2 = ((const float4*)(h2 + (size_t)(n + 2) * HID))[lane];
        float4 r3 = ((const float4*)(h2 + (size_t)(n + 3) * HID))[lane];
        acc8(acc, r0); acc8(acc, r1); acc8(acc, r2); acc8(acc, r3);
    }
    for (; n < s1; n++)
        acc8(acc, ((const float4*)(h2 + (size_t)n * HID))[lane]);
    float* orow = hg + (size_t)g * HID + lane * 8;
    ((float4*)orow)[0] = make_float4(acc[0], acc[1], acc[2], acc[3]);
    ((float4*)orow)[1] = make_float4(acc[4], acc[5], acc[6], acc[7]);
}

// xinb[g, c] (bf16, stride 768) = c<512: hg/cnt | c<712: desc | else 0
template<typename FT>
__device__ __forceinline__ void build_xin_body(const float* __restrict__ hg,
                                               const int* __restrict__ gstart,
                                               const FT* __restrict__ desc,
                                               bf16* __restrict__ xinb)
{
    int idx = blockIdx.x * 256 + threadIdx.x;
    if (idx >= N_GRAPHS * XIN_PAD) return;
    int g = idx / XIN_PAD;
    int c = idx - g * XIN_PAD;
    float v;
    if (c < HID) {
        float cnt = (float)(gstart[g + 1] - gstart[g]);
        v = hg[(size_t)g * HID + c] / (cnt > 1.0f ? cnt : 1.0f);
    } else if (c < XIN_DIM) {
        v = ldf(desc, (size_t)g * N_DESC + (c - HID));
    } else {
        v = 0.f;
    }
    xinb[idx] = __float2bfloat16(v);
}

__global__ __launch_bounds__(256)
void build_xin_kernel(const float* __restrict__ hg, const int* __restrict__ gstart,
                      const void* __restrict__ desc, bf16* __restrict__ xinb,
                      const int* __restrict__ flag)
{
    if (*flag) build_xin_body(hg, gstart, (const bf16*)desc, xinb);
    else       build_xin_body(hg, gstart, (const float*)desc, xinb);
}

// out[g, c] = x2b[g,:100] @ cw[:,c] + cb[c]; output dtype follows flag
template<typename FT>
__device__ __forceinline__ void final_layer_body(const bf16* __restrict__ x2b,
                                                 const FT* __restrict__ cw,
                                                 const FT* __restrict__ cb,
                                                 FT* __restrict__ out)
{
    int i = blockIdx.x * 256 + threadIdx.x;
    if (i >= N_GRAPHS * N_CLASSES) return;
    int r = i >> 1, c = i & 1;
    float acc = ldf(cb, c);
    const bf16* xrow = x2b + (size_t)r * HID;   // stride 512, cols 0..99 valid
#pragma unroll 4
    for (int k = 0; k < MLP2_OUT; k++)
        acc += __bfloat162float(xrow[k]) * ldf(cw, k * N_CLASSES + c);
    if constexpr (sizeof(FT) == 2) out[i] = __float2bfloat16(acc);
    else                           out[i] = acc;
}

__global__ __launch_bounds__(256)
void final_layer_kernel(const bf16* __restrict__ x2b, const void* __restrict__ cw,
                        const void* __restrict__ cb, void* __restrict__ out,
                        const int* __restrict__ flag)
{
    if (*flag) final_layer_body(x2b, (const bf16*)cw, (const bf16*)cb, (bf16*)out);
    else       final_layer_body(x2b, (const float*)cw, (const float*)cb, (float*)out);
}

// ---------------------------------------------------------------------------
static inline size_t align_up(size_t x, size_t a) { return (x + a - 1) & ~(a - 1); }
static inline int swgrid(int nrt, int nct) { return ((nrt + 7) / 8) * 8 * nct; }

extern "C" void kernel_launch(void* const* d_in, const int* in_sizes, int n_in,
                              void* d_out, int out_size, void* d_ws, size_t ws_size,
                              hipStream_t stream)
{
    const void* features    = d_in[0];
    const void* descriptors = d_in[1];
    const int*  src         = (const int*)d_in[2];
    const int*  dst         = (const int*)d_in[3];
    const int*  node2graph  = (const int*)d_in[4];
    const void* W1          = d_in[5];
    const void* b1          = d_in[6];
    const void* W2          = d_in[7];
    const void* b2          = d_in[8];
    const void* lw1         = d_in[9];
    const void* lb1         = d_in[10];
    const void* lw2         = d_in[11];
    const void* lb2         = d_in[12];
    const void* cw          = d_in[13];
    const void* cb          = d_in[14];
    (void)in_sizes; (void)n_in; (void)out_size; (void)ws_size;

    // ---- Workspace layout (fixed ~218 MB; proven ws >= ~239 MB) ----
    // R_A (102.4 MB): agg1 bf16 [100000,128] -> aggc bf16 [100000,512]
    //                 -> head buffers (xinb @0, x1b @8MB, x2b @16MB)
    // R_B (102.4 MB): h1 bf16 [100000,512] -> h2 bf16 [100000,512]
    char* ws = (char*)d_ws;
    size_t off = 0;
    bf16* agg1 = (bf16*)(ws + off);
    bf16* aggc = (bf16*)(ws + off);
    bf16* xinb = (bf16*)(ws + off);
    bf16* x1b  = (bf16*)(ws + off + (size_t)8 * 1024 * 1024);
    bf16* x2b  = (bf16*)(ws + off + (size_t)16 * 1024 * 1024);
    off = align_up(off + (size_t)N_NODES * HID * sizeof(bf16), 256);   // 102.4 MB
    bf16* h1 = (bf16*)(ws + off);
    bf16* h2 = (bf16*)(ws + off);   // h1 dead after gather_h -> reuse for h2
    off = align_up(off + (size_t)N_NODES * HID * sizeof(bf16), 256);   // +102.4 MB
    float* hg = (float*)(ws + off);
    off = align_up(off + (size_t)N_GRAPHS * HID * sizeof(float), 256); // +8.19 MB
    int* dflag = (int*)(ws + off);          off = align_up(off + 256, 256);
    int* edge_start = (int*)(ws + off);     off = align_up(off + (N_NODES + 1) * 4, 256);
    int* cursor = (int*)(ws + off);         off = align_up(off + N_NODES * 4, 256);
    int* csr_src = (int*)(ws + off);        off = align_up(off + N_EDGES * 4, 256);
    int* part = (int*)(ws + off);           off = align_up(off + NCHK * 4, 256);
    int* deg = (int*)(ws + off);            off = align_up(off + N_NODES * 4, 256);
    int* gstart = (int*)(ws + off);         off = align_up(off + (N_GRAPHS + 1) * 4, 256);
    short* W1t  = (short*)(ws + off);       off = align_up(off + (size_t)HID * IN_DIM * 2, 256);
    short* W2t  = (short*)(ws + off);       off = align_up(off + (size_t)HID * HID * 2, 256);
    short* lw1t = (short*)(ws + off);       off = align_up(off + (size_t)512 * XIN_PAD * 2, 256);
    short* lw2t = (short*)(ws + off);       off = align_up(off + (size_t)128 * HID * 2, 256);
    float* b1f  = (float*)(ws + off);       off = align_up(off + 512 * 4, 256);
    float* b2f  = (float*)(ws + off);       off = align_up(off + 512 * 4, 256);
    float* lb1f = (float*)(ws + off);       off = align_up(off + 512 * 4, 256);
    float* lb2f = (float*)(ws + off);       off = align_up(off + 128 * 4, 256);

    // ---- Detect float-tensor dtype (flag: 0=fp32, 1=bf16) ----
    detect_dtype_kernel<<<1, 256, 0, stream>>>(
        (const unsigned*)features, (unsigned)(N_NODES * IN_DIM / 2), dflag);

    // ---- Weight prep (single runtime-dual-mode launch) ----
    prep_weights_kernel<<<(788096 + 255) / 256, 256, 0, stream>>>(
        W1, W2, lw1, lw2, b1, b2, lb1, lb2,
        W1t, W2t, lw1t, lw2t, b1f, b2f, lb1f, lb2f, dflag);

    // ---- CSR build (counting sort by dst) + graph ranges ----
    hipMemsetAsync(deg, 0, N_NODES * 4, stream);
    deg_kernel<<<(N_EDGES + 255) / 256, 256, 0, stream>>>(dst, deg);
    scan_partial_kernel<<<NCHK, 256, 0, stream>>>(deg, part);
    scan_parts_kernel<<<1, 1, 0, stream>>>(part, edge_start);
    scan_final_kernel<<<NCHK, 256, 0, stream>>>(deg, part, edge_start, cursor);
    fill_kernel<<<(N_EDGES + 255) / 256, 256, 0, stream>>>(src, dst, cursor, csr_src);
    gstart_kernel<<<(N_NODES + 256) / 256, 256, 0, stream>>>(node2graph, gstart);

    // ---- Layer 1: gather -> agg1 (bf16), MFMA GEMM -> h1 (bf16) ----
    gather_feat_kernel<<<N_NODES / 4, 256, 0, stream>>>(
        features, edge_start, csr_src, agg1, dflag);
    {
        int nrt = (N_NODES + 127) / 128;   // 782
        mfma_gemm_kernel<4><<<swgrid(nrt, 4), 256, 0, stream>>>(
            (const short*)agg1, W1t, b1f, h1, N_NODES, IN_DIM, nrt);
    }

    // ---- Layer 2: gather h1 -> aggc (bf16), MFMA GEMM -> h2, pool (no atomics)
    gather_h_kernel<<<N_NODES / 4, 256, 0, stream>>>(h1, edge_start, csr_src, aggc);
    {
        int nrt = (N_NODES + 127) / 128;
        mfma_gemm_kernel<4><<<swgrid(nrt, 4), 256, 0, stream>>>(
            (const short*)aggc, W2t, b2f, h2, N_NODES, HID, nrt);
    }
    pool_graph_kernel<<<N_GRAPHS / 4, 256, 0, stream>>>(h2, gstart, hg);

    // ---- Head (all MFMA; padded-K chaining) ----
    build_xin_kernel<<<(N_GRAPHS * XIN_PAD + 255) / 256, 256, 0, stream>>>(
        hg, gstart, descriptors, xinb, dflag);
    {   // x1b[4000,512] = relu(xinb[4000,768] @ lw1t^T + lb1f)
        int nrt = (N_GRAPHS + 127) / 128;  // 32
        mfma_gemm_kernel<4><<<swgrid(nrt, 4), 256, 0, stream>>>(
            (const short*)xinb, lw1t, lb1f, x1b, N_GRAPHS, XIN_PAD, nrt);
    }
    {   // x2b cols 0..127 (stride 512) = relu(x1b @ lw2t^T + lb2f)
        int nrt = (N_GRAPHS + 127) / 128;
        mfma_gemm_kernel<1><<<swgrid(nrt, 1), 256, 0, stream>>>(
            (const short*)x1b, lw2t, lb2f, x2b, N_GRAPHS, HID, nrt);
    }
    final_layer_kernel<<<(N_GRAPHS * N_CLASSES + 255) / 256, 256, 0, stream>>>(
        x2b, cw, cb, d_out, dflag);
}